// Round 2
// baseline (306.296 us; speedup 1.0000x reference)
//
#include <hip/hip_runtime.h>
#include <hip/hip_bf16.h>

// Fused causal MHA: qkv proj -> flash attention -> out proj, all bf16 MFMA.
// B=2 T=2048 D=1024 H=16 hd=64, scale=0.125 folded into Q (exact pow2).

typedef __bf16 bf16;
typedef float f32x4 __attribute__((ext_vector_type(4)));
typedef bf16 bf16x4 __attribute__((ext_vector_type(4)));
typedef bf16 bf16x8 __attribute__((ext_vector_type(8)));

#define B_ 2
#define T_ 2048
#define D_ 1024
#define H_ 16
#define HD_ 64

__device__ __forceinline__ f32x4 mfma16(bf16x8 a, bf16x8 b, f32x4 c) {
    return __builtin_amdgcn_mfma_f32_16x16x32_bf16(a, b, c, 0, 0, 0);
}

// async global->LDS, 16B per lane (wave-uniform LDS base + lane*16)
__device__ __forceinline__ void gload16(void* l, const void* g) {
    __builtin_amdgcn_global_load_lds(
        (const __attribute__((address_space(1))) unsigned int*)g,
        (__attribute__((address_space(3))) unsigned int*)l, 16, 0, 0);
}

// ---------------- cast kernels ----------------
__global__ __launch_bounds__(256) void cast_f32_bf16(const float* __restrict__ in,
                                                     bf16* __restrict__ out, int n4) {
    int i = blockIdx.x * 256 + threadIdx.x;
    if (i < n4) {
        float4 v = ((const float4*)in)[i];
        bf16x4 o = { (bf16)v.x, (bf16)v.y, (bf16)v.z, (bf16)v.w };
        ((bf16x4*)out)[i] = o;
    }
}

// in [R][C] f32 -> out [C][R] bf16
__global__ __launch_bounds__(256) void cast_transpose(const float* __restrict__ in,
                                                      bf16* __restrict__ out, int R, int C) {
    __shared__ float tile[32][33];
    int cx = blockIdx.x * 32 + threadIdx.x;
    int r0 = blockIdx.y * 32;
#pragma unroll
    for (int j = 0; j < 32; j += 8)
        tile[threadIdx.y + j][threadIdx.x] = in[(size_t)(r0 + threadIdx.y + j) * C + cx];
    __syncthreads();
    int rx = r0 + threadIdx.x;
    int c0 = blockIdx.x * 32;
#pragma unroll
    for (int j = 0; j < 32; j += 8)
        out[(size_t)(c0 + threadIdx.y + j) * R + rx] = (bf16)tile[threadIdx.x][threadIdx.y + j];
}

// V [bh][T][64] bf16 -> Vt [bh][64][T] bf16 (64x64 tiles, conflict-free LDS)
__global__ __launch_bounds__(256) void transpose_v(const bf16* __restrict__ vb,
                                                   bf16* __restrict__ vt) {
    __shared__ bf16 st[64 * 65];
    const int bh = blockIdx.y;
    const int t0 = blockIdx.x * 64;
    const int tid = threadIdx.x;
#pragma unroll
    for (int c = 0; c < 2; ++c) {
        int cid = tid + c * 256;
        int r = cid >> 3, col = (cid & 7) * 8;  // r = t-row, col = d
        bf16x8 v = *(const bf16x8*)&vb[((size_t)bh * T_ + t0 + r) * HD_ + col];
#pragma unroll
        for (int j = 0; j < 8; ++j) st[r * 65 + col + j] = v[j];
    }
    __syncthreads();
#pragma unroll
    for (int c = 0; c < 2; ++c) {
        int cid = tid + c * 256;
        int tg = cid & 7, d = cid >> 3;  // tcol = tg*8, d-row
        bf16x8 o;
#pragma unroll
        for (int j = 0; j < 8; ++j) o[j] = st[(tg * 8 + j) * 65 + d];
        *(bf16x8*)&vt[((size_t)bh * HD_ + d) * T_ + t0 + tg * 8] = o;
    }
}

// ---------------- 128x128 GEMM (m97 structure): C = A[M,K] * Bt[N,K]^T ----------------
// EPI 0: scatter qkv into per-head Q/K/V [B][H][T][64] bf16
// EPI 1: add bias, write f32 to out
template <int EPI>
__global__ __launch_bounds__(256) void gemm128(
    const bf16* __restrict__ A, const bf16* __restrict__ Bt,
    int M, int N, int K,
    bf16* __restrict__ qb, bf16* __restrict__ kb, bf16* __restrict__ vb,
    const float* __restrict__ bias, float* __restrict__ outf) {
    __shared__ bf16 sA[128 * 32];
    __shared__ bf16 sB[128 * 32];
    const int tid = threadIdx.x;
    const int wave = tid >> 6, lane = tid & 63;
    const int lr = lane & 15, kg4 = (lane >> 4) * 4;
    const int wr = (wave >> 1) * 64, wc = (wave & 1) * 64;
    const int m0 = blockIdx.x * 128, n0 = blockIdx.y * 128;

    // staging: thread t covers LDS bytes t*16 and (t+256)*16 (linear row-major [128][32])
    const int srow = tid >> 2, scol = (tid & 3) * 8;
    const bf16* gA0 = A + (size_t)(m0 + srow) * K + scol;
    const bf16* gA1 = A + (size_t)(m0 + 64 + srow) * K + scol;
    const bf16* gB0 = Bt + (size_t)(n0 + srow) * K + scol;
    const bf16* gB1 = Bt + (size_t)(n0 + 64 + srow) * K + scol;
    bf16* lA0 = &sA[tid * 8];
    bf16* lA1 = &sA[(tid + 256) * 8];
    bf16* lB0 = &sB[tid * 8];
    bf16* lB1 = &sB[(tid + 256) * 8];

    f32x4 z = {0.f, 0.f, 0.f, 0.f};
    f32x4 acc[4][4] = {{z, z, z, z}, {z, z, z, z}, {z, z, z, z}, {z, z, z, z}};

    for (int k0 = 0; k0 < K; k0 += 32) {
        __syncthreads();
        gload16(lA0, gA0 + k0);
        gload16(lA1, gA1 + k0);
        gload16(lB0, gB0 + k0);
        gload16(lB1, gB1 + k0);
        __syncthreads();
        bf16x8 af[4], bfr[4];
#pragma unroll
        for (int m = 0; m < 4; ++m) {
            const bf16* p = &sA[(wr + m * 16 + lr) * 32 + kg4];
            bf16x4 a0 = *(const bf16x4*)p;
            bf16x4 a1 = *(const bf16x4*)(p + 16);
            af[m] = __builtin_shufflevector(a0, a1, 0, 1, 2, 3, 4, 5, 6, 7);
        }
#pragma unroll
        for (int n = 0; n < 4; ++n) {
            const bf16* p = &sB[(wc + n * 16 + lr) * 32 + kg4];
            bf16x4 b0 = *(const bf16x4*)p;
            bf16x4 b1 = *(const bf16x4*)(p + 16);
            bfr[n] = __builtin_shufflevector(b0, b1, 0, 1, 2, 3, 4, 5, 6, 7);
        }
#pragma unroll
        for (int m = 0; m < 4; ++m)
#pragma unroll
            for (int n = 0; n < 4; ++n) acc[m][n] = mfma16(af[m], bfr[n], acc[m][n]);
    }

#pragma unroll
    for (int m = 0; m < 4; ++m)
#pragma unroll
        for (int n = 0; n < 4; ++n)
#pragma unroll
            for (int r = 0; r < 4; ++r) {
                int row = m0 + wr + m * 16 + kg4 + r;
                int col = n0 + wc + n * 16 + lr;
                float v = acc[m][n][r];
                if (EPI == 0) {
                    int part = col >> 10, h = (col >> 6) & 15, d = col & 63;
                    int b = row >> 11, t = row & (T_ - 1);
                    size_t idx = ((size_t)(b * H_ + h) * T_ + t) * HD_ + d;
                    bf16* dst = (part == 0) ? qb : (part == 1) ? kb : vb;
                    dst[idx] = (bf16)v;
                } else {
                    outf[(size_t)row * N + col] = v + bias[col];
                }
            }
}

// ---------------- flash attention ----------------
// grid: (T/64 balanced-mapped, B*H); block 256 = 4 waves, wave w owns 16 q-rows.
// K and Vt double-buffered in LDS; 1 barrier per KV tile; prefetch loads issued
// before compute (T14 async-STAGE split).
__global__ __launch_bounds__(256) void attn_kernel(
    const bf16* __restrict__ qb, const bf16* __restrict__ kb,
    const bf16* __restrict__ vtb, bf16* __restrict__ ob) {
    constexpr int NT = T_ / 64;  // 32
    constexpr int SK = 72;       // row stride for sK/sV (144B, 16B-aligned)
    constexpr int SP = 68;       // sP row stride
    __shared__ bf16 sK[2][64 * SK];
    __shared__ bf16 sV[2][64 * SK];
    __shared__ bf16 sP[4][16 * SP];

    const int bx = blockIdx.x;
    const int qt = (bx & 1) ? (bx >> 1) : (NT - 1 - (bx >> 1));  // balanced pairing
    const int bh = blockIdx.y;
    const int b = bh >> 4, h = bh & 15;
    const int tid = threadIdx.x, wave = tid >> 6, lane = tid & 63;
    const int lr = lane & 15, kg4 = (lane >> 4) * 4;
    const bf16* Qg = qb + (size_t)bh * (T_ * HD_);
    const bf16* Kg = kb + (size_t)bh * (T_ * HD_);
    const bf16* Vtg = vtb + (size_t)bh * (HD_ * T_);  // [64 d][T]

    // staging coords: cid = tid + c*256; row = cid>>3, col = (cid&7)*8
    const int r0s = tid >> 3, c0s = (tid & 7) * 8;          // chunk 0
    const int r1s = (tid + 256) >> 3, c1s = c0s;            // chunk 1 (same col, row+32)

    // Q fragments (2 K-chunks of 32), scale 0.125 folded in (exact)
    bf16x8 qf[2];
    {
        int qrow = qt * 64 + wave * 16 + lr;
#pragma unroll
        for (int c = 0; c < 2; ++c) {
            bf16x4 q0 = *(const bf16x4*)&Qg[(size_t)qrow * HD_ + c * 32 + kg4];
            bf16x4 q1 = *(const bf16x4*)&Qg[(size_t)qrow * HD_ + c * 32 + 16 + kg4];
            bf16x8 q8 = __builtin_shufflevector(q0, q1, 0, 1, 2, 3, 4, 5, 6, 7);
#pragma unroll
            for (int e = 0; e < 8; ++e) q8[e] = (bf16)((float)q8[e] * 0.125f);
            qf[c] = q8;
        }
    }

    f32x4 z = {0.f, 0.f, 0.f, 0.f};
    f32x4 o[4] = {z, z, z, z};
    float m[4] = {-__builtin_inff(), -__builtin_inff(), -__builtin_inff(), -__builtin_inff()};
    float lsum[4] = {0.f, 0.f, 0.f, 0.f};

    // prologue: stage tile 0 into buffer 0
    {
        bf16x8 k0v = *(const bf16x8*)&Kg[(size_t)r0s * HD_ + c0s];
        bf16x8 k1v = *(const bf16x8*)&Kg[(size_t)r1s * HD_ + c1s];
        bf16x8 v0v = *(const bf16x8*)&Vtg[(size_t)r0s * T_ + c0s];
        bf16x8 v1v = *(const bf16x8*)&Vtg[(size_t)r1s * T_ + c1s];
        *(bf16x8*)&sK[0][r0s * SK + c0s] = k0v;
        *(bf16x8*)&sK[0][r1s * SK + c1s] = k1v;
        *(bf16x8*)&sV[0][r0s * SK + c0s] = v0v;
        *(bf16x8*)&sV[0][r1s * SK + c1s] = v1v;
    }
    __syncthreads();

    int cur = 0;
    for (int kt = 0; kt <= qt; ++kt) {
        // issue prefetch loads for kt+1 (overlap with compute below)
        bf16x8 pk0, pk1, pv0, pv1;
        const bool pf = kt < qt;
        if (pf) {
            int kb0 = (kt + 1) * 64;
            pk0 = *(const bf16x8*)&Kg[(size_t)(kb0 + r0s) * HD_ + c0s];
            pk1 = *(const bf16x8*)&Kg[(size_t)(kb0 + r1s) * HD_ + c1s];
            pv0 = *(const bf16x8*)&Vtg[(size_t)r0s * T_ + kb0 + c0s];
            pv1 = *(const bf16x8*)&Vtg[(size_t)r1s * T_ + kb0 + c1s];
        }

        // S = Q K^T  (D-layout: row q = kg4+r, col kv = nt*16+lr)
        f32x4 s[4] = {z, z, z, z};
#pragma unroll
        for (int c = 0; c < 2; ++c) {
#pragma unroll
            for (int nt = 0; nt < 4; ++nt) {
                const bf16* rb = &sK[cur][(nt * 16 + lr) * SK + c * 32 + kg4];
                bf16x4 b0 = *(const bf16x4*)rb;
                bf16x4 b1 = *(const bf16x4*)(rb + 16);
                s[nt] = mfma16(qf[c],
                               __builtin_shufflevector(b0, b1, 0, 1, 2, 3, 4, 5, 6, 7),
                               s[nt]);
            }
        }

        // causal mask (only diagonal tile)
        if (kt == qt) {
#pragma unroll
            for (int nt = 0; nt < 4; ++nt)
#pragma unroll
                for (int r = 0; r < 4; ++r)
                    if (nt * 16 + lr > wave * 16 + kg4 + r) s[nt][r] = -__builtin_inff();
        }

        // online softmax, per q-row (reg r); row spread over 16 lanes of same group
#pragma unroll
        for (int r = 0; r < 4; ++r) {
            float pm = fmaxf(fmaxf(s[0][r], s[1][r]), fmaxf(s[2][r], s[3][r]));
#pragma unroll
            for (int off = 1; off < 16; off <<= 1) pm = fmaxf(pm, __shfl_xor(pm, off));
            float mnew = fmaxf(m[r], pm);
            float fac = __expf(m[r] - mnew);  // first iter: exp(-inf)=0
            float rs = 0.f;
#pragma unroll
            for (int nt = 0; nt < 4; ++nt) {
                float p = __expf(s[nt][r] - mnew);
                s[nt][r] = p;
                rs += p;
            }
#pragma unroll
            for (int off = 1; off < 16; off <<= 1) rs += __shfl_xor(rs, off);
            lsum[r] = lsum[r] * fac + rs;
            m[r] = mnew;
#pragma unroll
            for (int nt = 0; nt < 4; ++nt) o[nt][r] *= fac;
        }

        // P (D-layout) -> per-wave LDS (no barrier needed: same-wave reuse)
#pragma unroll
        for (int nt = 0; nt < 4; ++nt)
#pragma unroll
            for (int r = 0; r < 4; ++r)
                sP[wave][(kg4 + r) * SP + nt * 16 + lr] = (bf16)s[nt][r];

        // O += P V  (contraction over kv, 2 chunks of 32)
#pragma unroll
        for (int c = 0; c < 2; ++c) {
            const bf16* rp = &sP[wave][lr * SP + c * 32 + kg4];
            bf16x4 p0 = *(const bf16x4*)rp;
            bf16x4 p1 = *(const bf16x4*)(rp + 16);
            bf16x8 pfr = __builtin_shufflevector(p0, p1, 0, 1, 2, 3, 4, 5, 6, 7);
#pragma unroll
            for (int nt = 0; nt < 4; ++nt) {
                const bf16* rv = &sV[cur][(nt * 16 + lr) * SK + c * 32 + kg4];
                bf16x4 v0 = *(const bf16x4*)rv;
                bf16x4 v1 = *(const bf16x4*)(rv + 16);
                o[nt] = mfma16(pfr,
                               __builtin_shufflevector(v0, v1, 0, 1, 2, 3, 4, 5, 6, 7),
                               o[nt]);
            }
        }

        // write prefetched tile into the other buffer, then single barrier
        if (pf) {
            int nb = cur ^ 1;
            *(bf16x8*)&sK[nb][r0s * SK + c0s] = pk0;
            *(bf16x8*)&sK[nb][r1s * SK + c1s] = pk1;
            *(bf16x8*)&sV[nb][r0s * SK + c0s] = pv0;
            *(bf16x8*)&sV[nb][r1s * SK + c1s] = pv1;
        }
        __syncthreads();
        cur ^= 1;
    }

    // epilogue: ob [B][T][H*64] bf16
#pragma unroll
    for (int r = 0; r < 4; ++r) {
        float inv = 1.f / lsum[r];
        int t = qt * 64 + wave * 16 + kg4 + r;
#pragma unroll
        for (int nt = 0; nt < 4; ++nt)
            ob[((size_t)(b * T_ + t)) * D_ + h * HD_ + nt * 16 + lr] =
                (bf16)(o[nt][r] * inv);
    }
}

// ---------------- launch ----------------
extern "C" void kernel_launch(void* const* d_in, const int* in_sizes, int n_in,
                              void* d_out, int out_size, void* d_ws, size_t ws_size,
                              hipStream_t stream) {
    const float* x = (const float*)d_in[0];
    const float* w_qkv = (const float*)d_in[1];
    const float* w_proj = (const float*)d_in[2];
    const float* b_proj = (const float*)d_in[3];
    float* out = (float*)d_out;
    char* ws = (char*)d_ws;

    // ws layout (40 MB total, aliased by liveness):
    bf16* xb = (bf16*)(ws);                 // [4096][1024]  8MB ; dead after GEMM1
    bf16* ob = (bf16*)(ws);                 // alias: attn out (written after xb dead)
    bf16* wqkvt = (bf16*)(ws + 8388608);    // [3072][1024]  6MB ; dead after GEMM1
    bf16* vtbuf = (bf16*)(ws + 8388608);    // alias: [bh][64][T] 8MB (written after GEMM1)
    bf16* qbuf = (bf16*)(ws + 16777216);    // [bh][T][64]   8MB ; dead after attn
    bf16* wprojt = (bf16*)(ws + 16777216);  // alias: [1024][1024] 2MB (written after attn)
    bf16* kbuf = (bf16*)(ws + 25165824);    // [bh][T][64]   8MB
    bf16* vbuf = (bf16*)(ws + 33554432);    // [bh][T][64]   8MB

    cast_f32_bf16<<<4096, 256, 0, stream>>>(x, xb, (B_ * T_ * D_) / 4);
    dim3 tb(32, 8);
    cast_transpose<<<dim3(3 * D_ / 32, D_ / 32), tb, 0, stream>>>(w_qkv, wqkvt, D_, 3 * D_);

    gemm128<0><<<dim3((B_ * T_) / 128, (3 * D_) / 128), 256, 0, stream>>>(
        xb, wqkvt, B_ * T_, 3 * D_, D_, qbuf, kbuf, vbuf, nullptr, nullptr);

    transpose_v<<<dim3(T_ / 64, B_ * H_), 256, 0, stream>>>(vbuf, vtbuf);

    attn_kernel<<<dim3(T_ / 64, B_ * H_), 256, 0, stream>>>(qbuf, kbuf, vtbuf, ob);

    cast_transpose<<<dim3(D_ / 32, D_ / 32), tb, 0, stream>>>(w_proj, wprojt, D_, D_);

    gemm128<1><<<dim3((B_ * T_) / 128, D_ / 128), 256, 0, stream>>>(
        ob, wprojt, B_ * T_, D_, D_, nullptr, nullptr, nullptr, b_proj, out);
}

// Round 3
// 211.220 us; speedup vs baseline: 1.4501x; 1.4501x over previous
//
#include <hip/hip_runtime.h>
#include <hip/hip_bf16.h>

// Fused causal MHA: qkv proj -> flash attention -> out proj, all bf16 MFMA.
// B=2 T=2048 D=1024 H=16 hd=64, scale=0.125 folded into Q (exact pow2).

typedef __bf16 bf16;
typedef float f32x4 __attribute__((ext_vector_type(4)));
typedef float f32x16 __attribute__((ext_vector_type(16)));
typedef bf16 bf16x4 __attribute__((ext_vector_type(4)));
typedef bf16 bf16x8 __attribute__((ext_vector_type(8)));

#define B_ 2
#define T_ 2048
#define D_ 1024
#define H_ 16
#define HD_ 64

__device__ __forceinline__ f32x4 mfma16(bf16x8 a, bf16x8 b, f32x4 c) {
    return __builtin_amdgcn_mfma_f32_16x16x32_bf16(a, b, c, 0, 0, 0);
}
__device__ __forceinline__ f32x16 mfma32(bf16x8 a, bf16x8 b, f32x16 c) {
    return __builtin_amdgcn_mfma_f32_32x32x16_bf16(a, b, c, 0, 0, 0);
}

// async global->LDS, 16B per lane (wave-uniform LDS base + lane*16)
__device__ __forceinline__ void gload16(void* l, const void* g) {
    __builtin_amdgcn_global_load_lds(
        (const __attribute__((address_space(1))) unsigned int*)g,
        (__attribute__((address_space(3))) unsigned int*)l, 16, 0, 0);
}

__device__ __forceinline__ f32x16 z16() {
    f32x16 v;
#pragma unroll
    for (int i = 0; i < 16; ++i) v[i] = 0.f;
    return v;
}

// ---------------- cast kernels ----------------
__global__ __launch_bounds__(256) void cast_f32_bf16(const float* __restrict__ in,
                                                     bf16* __restrict__ out, int n4) {
    int i = blockIdx.x * 256 + threadIdx.x;
    if (i < n4) {
        float4 v = ((const float4*)in)[i];
        bf16x4 o = { (bf16)v.x, (bf16)v.y, (bf16)v.z, (bf16)v.w };
        ((bf16x4*)out)[i] = o;
    }
}

// in [R][C] f32 -> out [C][R] bf16
__global__ __launch_bounds__(256) void cast_transpose(const float* __restrict__ in,
                                                      bf16* __restrict__ out, int R, int C) {
    __shared__ float tile[32][33];
    int cx = blockIdx.x * 32 + threadIdx.x;
    int r0 = blockIdx.y * 32;
#pragma unroll
    for (int j = 0; j < 32; j += 8)
        tile[threadIdx.y + j][threadIdx.x] = in[(size_t)(r0 + threadIdx.y + j) * C + cx];
    __syncthreads();
    int rx = r0 + threadIdx.x;
    int c0 = blockIdx.x * 32;
#pragma unroll
    for (int j = 0; j < 32; j += 8)
        out[(size_t)(c0 + threadIdx.y + j) * R + rx] = (bf16)tile[threadIdx.x][threadIdx.y + j];
}

// V [bh][T][64] bf16 -> Vt [bh][64][T] bf16 (64x64 tiles, conflict-free LDS)
__global__ __launch_bounds__(256) void transpose_v(const bf16* __restrict__ vb,
                                                   bf16* __restrict__ vt) {
    __shared__ bf16 st[64 * 65];
    const int bh = blockIdx.y;
    const int t0 = blockIdx.x * 64;
    const int tid = threadIdx.x;
#pragma unroll
    for (int c = 0; c < 2; ++c) {
        int cid = tid + c * 256;
        int r = cid >> 3, col = (cid & 7) * 8;
        bf16x8 v = *(const bf16x8*)&vb[((size_t)bh * T_ + t0 + r) * HD_ + col];
#pragma unroll
        for (int j = 0; j < 8; ++j) st[r * 65 + col + j] = v[j];
    }
    __syncthreads();
#pragma unroll
    for (int c = 0; c < 2; ++c) {
        int cid = tid + c * 256;
        int tg = cid & 7, d = cid >> 3;
        bf16x8 o;
#pragma unroll
        for (int j = 0; j < 8; ++j) o[j] = st[(tg * 8 + j) * 65 + d];
        *(bf16x8*)&vt[((size_t)bh * HD_ + d) * T_ + t0 + tg * 8] = o;
    }
}

// ---------------- 128x128 GEMM (m97 structure): C = A[M,K] * Bt[N,K]^T ----------------
template <int EPI>
__global__ __launch_bounds__(256) void gemm128(
    const bf16* __restrict__ A, const bf16* __restrict__ Bt,
    int M, int N, int K,
    bf16* __restrict__ qb, bf16* __restrict__ kb, bf16* __restrict__ vb,
    const float* __restrict__ bias, float* __restrict__ outf) {
    __shared__ bf16 sA[128 * 32];
    __shared__ bf16 sB[128 * 32];
    const int tid = threadIdx.x;
    const int wave = tid >> 6, lane = tid & 63;
    const int lr = lane & 15, kg4 = (lane >> 4) * 4;
    const int wr = (wave >> 1) * 64, wc = (wave & 1) * 64;
    const int m0 = blockIdx.x * 128, n0 = blockIdx.y * 128;

    const int srow = tid >> 2, scol = (tid & 3) * 8;
    const bf16* gA0 = A + (size_t)(m0 + srow) * K + scol;
    const bf16* gA1 = A + (size_t)(m0 + 64 + srow) * K + scol;
    const bf16* gB0 = Bt + (size_t)(n0 + srow) * K + scol;
    const bf16* gB1 = Bt + (size_t)(n0 + 64 + srow) * K + scol;
    bf16* lA0 = &sA[tid * 8];
    bf16* lA1 = &sA[(tid + 256) * 8];
    bf16* lB0 = &sB[tid * 8];
    bf16* lB1 = &sB[(tid + 256) * 8];

    f32x4 z = {0.f, 0.f, 0.f, 0.f};
    f32x4 acc[4][4] = {{z, z, z, z}, {z, z, z, z}, {z, z, z, z}, {z, z, z, z}};

    for (int k0 = 0; k0 < K; k0 += 32) {
        __syncthreads();
        gload16(lA0, gA0 + k0);
        gload16(lA1, gA1 + k0);
        gload16(lB0, gB0 + k0);
        gload16(lB1, gB1 + k0);
        __syncthreads();
        bf16x8 af[4], bfr[4];
#pragma unroll
        for (int m = 0; m < 4; ++m) {
            const bf16* p = &sA[(wr + m * 16 + lr) * 32 + kg4];
            bf16x4 a0 = *(const bf16x4*)p;
            bf16x4 a1 = *(const bf16x4*)(p + 16);
            af[m] = __builtin_shufflevector(a0, a1, 0, 1, 2, 3, 4, 5, 6, 7);
        }
#pragma unroll
        for (int n = 0; n < 4; ++n) {
            const bf16* p = &sB[(wc + n * 16 + lr) * 32 + kg4];
            bf16x4 b0 = *(const bf16x4*)p;
            bf16x4 b1 = *(const bf16x4*)(p + 16);
            bfr[n] = __builtin_shufflevector(b0, b1, 0, 1, 2, 3, 4, 5, 6, 7);
        }
#pragma unroll
        for (int m = 0; m < 4; ++m)
#pragma unroll
            for (int n = 0; n < 4; ++n) acc[m][n] = mfma16(af[m], bfr[n], acc[m][n]);
    }

#pragma unroll
    for (int m = 0; m < 4; ++m)
#pragma unroll
        for (int n = 0; n < 4; ++n)
#pragma unroll
            for (int r = 0; r < 4; ++r) {
                int row = m0 + wr + m * 16 + kg4 + r;
                int col = n0 + wc + n * 16 + lr;
                float v = acc[m][n][r];
                if (EPI == 0) {
                    int part = col >> 10, h = (col >> 6) & 15, d = col & 63;
                    int b = row >> 11, t = row & (T_ - 1);
                    size_t idx = ((size_t)(b * H_ + h) * T_ + t) * HD_ + d;
                    bf16* dst = (part == 0) ? qb : (part == 1) ? kb : vb;
                    dst[idx] = (bf16)v;
                } else {
                    outf[(size_t)row * N + col] = v + bias[col];
                }
            }
}

// ---------------- flash attention v3: swapped-operand 32x32 MFMA ----------------
// Grid: 512 1D blocks; bh = bx&31; q-tile qt paired so bx and bx+256 sum to
// uniform work. Block = 4 waves, wave owns 32 q-rows (q = qs + (lane&31), lane-local).
// S^T = mfma32(K,Q): lane holds P^T[kv][q] for its q; softmax in-register
// (one shfl_xor(32) per reduce). O^T = mfma32(V^T, P^T): P^T B-frag is the lane's
// own C-regs (f(hi,e)=4hi+(e&3)+8(e>>2) packing) -> zero cross-lane, no P LDS.
__device__ __forceinline__ bf16x8 kread(const char* base, int row, int s, int hi) {
    int b = (row * 128 + s * 32 + hi * 16) ^ ((row & 7) << 4);
    return *(const bf16x8*)(base + b);
}
__device__ __forceinline__ bf16x8 vread(const char* base, int row, int s, int hi) {
    int sw = (row & 7) << 4;
    int b0 = (row * 128 + s * 32 + hi * 8) ^ sw;
    int b1 = (row * 128 + s * 32 + hi * 8 + 16) ^ sw;
    bf16x4 lo = *(const bf16x4*)(base + b0);
    bf16x4 hi4 = *(const bf16x4*)(base + b1);
    return __builtin_shufflevector(lo, hi4, 0, 1, 2, 3, 4, 5, 6, 7);
}

__global__ __launch_bounds__(256) void attn_kernel(
    const bf16* __restrict__ qb, const bf16* __restrict__ kb,
    const bf16* __restrict__ vtb, bf16* __restrict__ ob) {
    __shared__ bf16 sK2[2][4096];  // [64 kv][64 hd], 128B rows, XOR-swizzled
    __shared__ bf16 sV2[2][4096];  // [64 d][64 kv], 128B rows, XOR-swizzled

    const int bx = blockIdx.x;
    const int bh = bx & 31;
    const int qt = (bx < 256) ? ((bx >> 5) & 7) : (15 - ((bx >> 5) & 7));
    const int b = bh >> 4, h = bh & 15;
    const int tid = threadIdx.x, wave = tid >> 6, lane = tid & 63;
    const int ln = lane & 31, hi = lane >> 5;
    const int qs = qt * 128 + wave * 32;  // wave's q strip [qs, qs+32)
    const int qrow = qs + ln;             // this lane's q row
    const int ntiles = 2 * qt + 2;

    const bf16* Qg = qb + (size_t)bh * (T_ * HD_);
    const bf16* Kg = kb + (size_t)bh * (T_ * HD_);
    const bf16* Vtg = vtb + (size_t)bh * (HD_ * T_);

    // Q fragments (hoisted, scale 0.125 folded in): qf[s][e] = Q[qrow][16s+8hi+e]
    bf16x8 qf[4];
#pragma unroll
    for (int s = 0; s < 4; ++s) {
        bf16x8 v = *(const bf16x8*)&Qg[(size_t)qrow * HD_ + s * 16 + hi * 8];
#pragma unroll
        for (int e = 0; e < 8; ++e) v[e] = (bf16)((float)v[e] * 0.125f);
        qf[s] = v;
    }

    // staging: thread covers rows srow, srow+32; 16B col chunk (tid&7)
    const int srow = tid >> 3;
    const int scol = (tid & 7) * 8;  // elems
    const int kw0 = (srow * 128 + (tid & 7) * 16) ^ ((srow & 7) << 4);
    const int kw1 = ((srow + 32) * 128 + (tid & 7) * 16) ^ ((srow & 7) << 4);

    // prologue: stage tile 0 into buffer 0
    {
        bf16x8 k0 = *(const bf16x8*)&Kg[(size_t)srow * HD_ + scol];
        bf16x8 k1 = *(const bf16x8*)&Kg[(size_t)(srow + 32) * HD_ + scol];
        bf16x8 v0 = *(const bf16x8*)&Vtg[(size_t)srow * T_ + scol];
        bf16x8 v1 = *(const bf16x8*)&Vtg[(size_t)(srow + 32) * T_ + scol];
        *(bf16x8*)((char*)sK2[0] + kw0) = k0;
        *(bf16x8*)((char*)sK2[0] + kw1) = k1;
        *(bf16x8*)((char*)sV2[0] + kw0) = v0;
        *(bf16x8*)((char*)sV2[0] + kw1) = v1;
    }
    __syncthreads();

    const float NINF = -__builtin_inff();
    f32x16 oA = z16(), oB = z16();
    float mR = NINF, lR = 0.f;
    int cur = 0;

    for (int t = 0; t < ntiles; ++t) {
        // T14: issue next-tile global loads before compute
        bf16x8 kr0, kr1, vr0, vr1;
        const bool pf = (t + 1) < ntiles;
        if (pf) {
            int kv0 = (t + 1) * 64;
            kr0 = *(const bf16x8*)&Kg[(size_t)(kv0 + srow) * HD_ + scol];
            kr1 = *(const bf16x8*)&Kg[(size_t)(kv0 + srow + 32) * HD_ + scol];
            vr0 = *(const bf16x8*)&Vtg[(size_t)srow * T_ + kv0 + scol];
            vr1 = *(const bf16x8*)&Vtg[(size_t)(srow + 32) * T_ + kv0 + scol];
        }

        if (64 * t <= qs + 31) {  // wave not fully masked for this tile
            const char* kbase = (const char*)sK2[cur];
            const char* vbase = (const char*)sV2[cur];

            // S^T: p0 = K[kv 0..31] x Q, p1 = K[kv 32..63] x Q
            f32x16 p0 = z16(), p1 = z16();
#pragma unroll
            for (int s = 0; s < 4; ++s) {
                bf16x8 a0 = kread(kbase, ln, s, hi);
                bf16x8 a1 = kread(kbase, ln + 32, s, hi);
                p0 = mfma32(a0, qf[s], p0);
                p1 = mfma32(a1, qf[s], p1);
            }

            // causal mask: kv = 64t + 32*blk + (r&3)+8*(r>>2)+4*hi ; mask kv > qrow
            if (64 * t + 63 > qs) {
                int kvb = 64 * t + 4 * hi;
#pragma unroll
                for (int r = 0; r < 16; ++r) {
                    int kvr = kvb + (r & 3) + 8 * (r >> 2);
                    if (kvr > qrow) p0[r] = NINF;
                    if (kvr + 32 > qrow) p1[r] = NINF;
                }
            }

            // online softmax (q is lane-local; one shfl per reduce)
            float mx0 = NINF, mx1 = NINF, mx2 = NINF, mx3 = NINF;
#pragma unroll
            for (int r = 0; r < 16; r += 4) {
                mx0 = fmaxf(mx0, p0[r]);     mx1 = fmaxf(mx1, p0[r + 1]);
                mx2 = fmaxf(mx2, p0[r + 2]); mx3 = fmaxf(mx3, p0[r + 3]);
                mx0 = fmaxf(mx0, p1[r]);     mx1 = fmaxf(mx1, p1[r + 1]);
                mx2 = fmaxf(mx2, p1[r + 2]); mx3 = fmaxf(mx3, p1[r + 3]);
            }
            float pm = fmaxf(fmaxf(mx0, mx1), fmaxf(mx2, mx3));
            pm = fmaxf(pm, __shfl_xor(pm, 32));
            float mnew = fmaxf(mR, pm);
            float fac = __expf(mR - mnew);
            mR = mnew;
            float s0 = 0.f, s1 = 0.f, s2 = 0.f, s3 = 0.f;
#pragma unroll
            for (int r = 0; r < 16; r += 4) {
                p0[r] = __expf(p0[r] - mnew);         s0 += p0[r];
                p0[r + 1] = __expf(p0[r + 1] - mnew); s1 += p0[r + 1];
                p0[r + 2] = __expf(p0[r + 2] - mnew); s2 += p0[r + 2];
                p0[r + 3] = __expf(p0[r + 3] - mnew); s3 += p0[r + 3];
                p1[r] = __expf(p1[r] - mnew);         s0 += p1[r];
                p1[r + 1] = __expf(p1[r + 1] - mnew); s1 += p1[r + 1];
                p1[r + 2] = __expf(p1[r + 2] - mnew); s2 += p1[r + 2];
                p1[r + 3] = __expf(p1[r + 3] - mnew); s3 += p1[r + 3];
            }
            float rs = (s0 + s1) + (s2 + s3);
            rs += __shfl_xor(rs, 32);
            lR = lR * fac + rs;
#pragma unroll
            for (int r = 0; r < 16; ++r) { oA[r] *= fac; oB[r] *= fac; }

            // pack P^T fragments (lane's own regs; f(hi,e)=4hi+(e&3)+8(e>>2))
            bf16x8 pa0, pa1, pa2, pa3;
#pragma unroll
            for (int e = 0; e < 8; ++e) {
                pa0[e] = (bf16)p0[e];
                pa1[e] = (bf16)p0[8 + e];
                pa2[e] = (bf16)p1[e];
                pa3[e] = (bf16)p1[8 + e];
            }

            // O^T += V^T x P^T  (oA: d 0..31, oB: d 32..63)
#pragma unroll
            for (int s = 0; s < 4; ++s) {
                bf16x8 pas = (s == 0) ? pa0 : (s == 1) ? pa1 : (s == 2) ? pa2 : pa3;
                oA = mfma32(vread(vbase, ln, s, hi), pas, oA);
                oB = mfma32(vread(vbase, ln + 32, s, hi), pas, oB);
            }
        }

        // write prefetched tile into other buffer; single barrier per tile
        if (pf) {
            int nb = cur ^ 1;
            *(bf16x8*)((char*)sK2[nb] + kw0) = kr0;
            *(bf16x8*)((char*)sK2[nb] + kw1) = kr1;
            *(bf16x8*)((char*)sV2[nb] + kw0) = vr0;
            *(bf16x8*)((char*)sV2[nb] + kw1) = vr1;
        }
        __syncthreads();
        cur ^= 1;
    }

    // epilogue: lane owns full q-row qrow; d = (r&3)+8(r>>2)+4hi (+32 for oB)
    float inv = 1.f / lR;
    bf16* orow = ob + ((size_t)(b * T_ + qrow)) * D_ + h * HD_;
#pragma unroll
    for (int g = 0; g < 4; ++g) {
        bf16x4 w, w2;
#pragma unroll
        for (int j = 0; j < 4; ++j) {
            w[j] = (bf16)(oA[4 * g + j] * inv);
            w2[j] = (bf16)(oB[4 * g + j] * inv);
        }
        *(bf16x4*)&orow[4 * hi + 8 * g] = w;
        *(bf16x4*)&orow[32 + 4 * hi + 8 * g] = w2;
    }
}

// ---------------- launch ----------------
extern "C" void kernel_launch(void* const* d_in, const int* in_sizes, int n_in,
                              void* d_out, int out_size, void* d_ws, size_t ws_size,
                              hipStream_t stream) {
    const float* x = (const float*)d_in[0];
    const float* w_qkv = (const float*)d_in[1];
    const float* w_proj = (const float*)d_in[2];
    const float* b_proj = (const float*)d_in[3];
    float* out = (float*)d_out;
    char* ws = (char*)d_ws;

    // ws layout (40 MB total, aliased by liveness):
    bf16* xb = (bf16*)(ws);                 // [4096][1024]  8MB ; dead after GEMM1
    bf16* ob = (bf16*)(ws);                 // alias: attn out (written after xb dead)
    bf16* wqkvt = (bf16*)(ws + 8388608);    // [3072][1024]  6MB ; dead after GEMM1
    bf16* vtbuf = (bf16*)(ws + 8388608);    // alias: [bh][64][T] 8MB (written after GEMM1)
    bf16* qbuf = (bf16*)(ws + 16777216);    // [bh][T][64]   8MB ; dead after attn
    bf16* wprojt = (bf16*)(ws + 16777216);  // alias: [1024][1024] 2MB (written after attn)
    bf16* kbuf = (bf16*)(ws + 25165824);    // [bh][T][64]   8MB
    bf16* vbuf = (bf16*)(ws + 33554432);    // [bh][T][64]   8MB

    cast_f32_bf16<<<4096, 256, 0, stream>>>(x, xb, (B_ * T_ * D_) / 4);
    dim3 tb(32, 8);
    cast_transpose<<<dim3(3 * D_ / 32, D_ / 32), tb, 0, stream>>>(w_qkv, wqkvt, D_, 3 * D_);

    gemm128<0><<<dim3((B_ * T_) / 128, (3 * D_) / 128), 256, 0, stream>>>(
        xb, wqkvt, B_ * T_, 3 * D_, D_, qbuf, kbuf, vbuf, nullptr, nullptr);

    transpose_v<<<dim3(T_ / 64, B_ * H_), 256, 0, stream>>>(vbuf, vtbuf);

    attn_kernel<<<512, 256, 0, stream>>>(qbuf, kbuf, vtbuf, ob);

    cast_transpose<<<dim3(D_ / 32, D_ / 32), tb, 0, stream>>>(w_proj, wprojt, D_, D_);

    gemm128<1><<<dim3((B_ * T_) / 128, D_ / 128), 256, 0, stream>>>(
        ob, wprojt, B_ * T_, D_, D_, nullptr, nullptr, nullptr, b_proj, out);
}

// Round 4
// 141.146 us; speedup vs baseline: 2.1701x; 1.4965x over previous
//
#include <hip/hip_runtime.h>
#include <hip/hip_bf16.h>

// Fused causal MHA: qkv proj -> flash attention -> out proj, all bf16 MFMA.
// B=2 T=2048 D=1024 H=16 hd=64, scale=0.125 folded into Q (exact pow2).

typedef __bf16 bf16;
typedef float f32x4 __attribute__((ext_vector_type(4)));
typedef float f32x16 __attribute__((ext_vector_type(16)));
typedef bf16 bf16x4 __attribute__((ext_vector_type(4)));
typedef bf16 bf16x8 __attribute__((ext_vector_type(8)));

#define B_ 2
#define T_ 2048
#define D_ 1024
#define H_ 16
#define HD_ 64

__device__ __forceinline__ f32x16 mfma32(bf16x8 a, bf16x8 b, f32x16 c) {
    return __builtin_amdgcn_mfma_f32_32x32x16_bf16(a, b, c, 0, 0, 0);
}

// async global->LDS, 16B per lane (wave-uniform LDS base + lane*16)
__device__ __forceinline__ void gload16(void* l, const void* g) {
    __builtin_amdgcn_global_load_lds(
        (const __attribute__((address_space(1))) unsigned int*)g,
        (__attribute__((address_space(3))) unsigned int*)l, 16, 0, 0);
}

__device__ __forceinline__ f32x16 z16() {
    f32x16 v;
#pragma unroll
    for (int i = 0; i < 16; ++i) v[i] = 0.f;
    return v;
}

// ---------------- cast kernels ----------------
__global__ __launch_bounds__(256) void cast_f32_bf16(const float* __restrict__ in,
                                                     bf16* __restrict__ out, int n4) {
    int i = blockIdx.x * 256 + threadIdx.x;
    if (i < n4) {
        float4 v = ((const float4*)in)[i];
        bf16x4 o = { (bf16)v.x, (bf16)v.y, (bf16)v.z, (bf16)v.w };
        ((bf16x4*)out)[i] = o;
    }
}

// in [R][C] f32 -> out [C][R] bf16
__global__ __launch_bounds__(256) void cast_transpose(const float* __restrict__ in,
                                                      bf16* __restrict__ out, int R, int C) {
    __shared__ float tile[32][33];
    int cx = blockIdx.x * 32 + threadIdx.x;
    int r0 = blockIdx.y * 32;
#pragma unroll
    for (int j = 0; j < 32; j += 8)
        tile[threadIdx.y + j][threadIdx.x] = in[(size_t)(r0 + threadIdx.y + j) * C + cx];
    __syncthreads();
    int rx = r0 + threadIdx.x;
    int c0 = blockIdx.x * 32;
#pragma unroll
    for (int j = 0; j < 32; j += 8)
        out[(size_t)(c0 + threadIdx.y + j) * R + rx] = (bf16)tile[threadIdx.x][threadIdx.y + j];
}

// V [bh][T][64] bf16 -> Vt [bh][64][T] bf16 (64x64 tiles, conflict-free LDS)
__global__ __launch_bounds__(256) void transpose_v(const bf16* __restrict__ vb,
                                                   bf16* __restrict__ vt) {
    __shared__ bf16 st[64 * 65];
    const int bh = blockIdx.y;
    const int t0 = blockIdx.x * 64;
    const int tid = threadIdx.x;
#pragma unroll
    for (int c = 0; c < 2; ++c) {
        int cid = tid + c * 256;
        int r = cid >> 3, col = (cid & 7) * 8;
        bf16x8 v = *(const bf16x8*)&vb[((size_t)bh * T_ + t0 + r) * HD_ + col];
#pragma unroll
        for (int j = 0; j < 8; ++j) st[r * 65 + col + j] = v[j];
    }
    __syncthreads();
#pragma unroll
    for (int c = 0; c < 2; ++c) {
        int cid = tid + c * 256;
        int tg = cid & 7, d = cid >> 3;
        bf16x8 o;
#pragma unroll
        for (int j = 0; j < 8; ++j) o[j] = st[(tg * 8 + j) * 65 + d];
        *(bf16x8*)&vt[((size_t)bh * HD_ + d) * T_ + t0 + tg * 8] = o;
    }
}

// ---------------- GEMM: C[M,N] = A[M,K] * Bt[N,K]^T, 32x32x16 MFMA ----------------
// Block tile 128 x (64*NWN); 4 waves (2M x 2N), per-wave 64 x (32*NWN).
// BK=64. LDS layout: [row][64] with chunk swizzle p = g ^ (row&7) (16B chunks);
// staged via global_load_lds with inverse-permuted SOURCE (linear dest, rule #21).
// Fragments: 16B-contiguous k-packing (hi,e)->k=16s+8hi+e, identical for A and B
// (self-consistent => correct; hardware-validated in attn kernel).
// EPI 0: scatter qkv into per-head Q/K/V [B][H][T][64] bf16 ; EPI 1: +bias, f32 out.
template <int NWN, int EPI>
__global__ __launch_bounds__(256) void gemm_k(
    const bf16* __restrict__ A, const bf16* __restrict__ Bt,
    int M, int N, int K,
    bf16* __restrict__ qb, bf16* __restrict__ kb, bf16* __restrict__ vb,
    const float* __restrict__ bias, float* __restrict__ outf) {
    constexpr int BN = 64 * NWN;
    __shared__ bf16 sA[128 * 64];
    __shared__ bf16 sB[BN * 64];
    const int tid = threadIdx.x;
    const int wave = tid >> 6, lane = tid & 63;
    const int ln = lane & 31, hi = lane >> 5;
    const int wr = (wave >> 1) * 64;
    const int wc = (wave & 1) * (32 * NWN);
    const int m0 = blockIdx.x * 128, n0 = blockIdx.y * BN;

    f32x16 acc[2][NWN];
#pragma unroll
    for (int mi = 0; mi < 2; ++mi)
#pragma unroll
        for (int ni = 0; ni < NWN; ++ni) acc[mi][ni] = z16();

    for (int k0 = 0; k0 < K; k0 += 64) {
        __syncthreads();
#pragma unroll
        for (int j = 0; j < 4; ++j) {
            int c = tid + 256 * j;
            int r = c >> 3, g = (c & 7) ^ (r & 7);
            gload16(&sA[c * 8], A + (size_t)(m0 + r) * K + k0 + 8 * g);
        }
#pragma unroll
        for (int j = 0; j < 2 * NWN; ++j) {
            int c = tid + 256 * j;
            int r = c >> 3, g = (c & 7) ^ (r & 7);
            gload16(&sB[c * 8], Bt + (size_t)(n0 + r) * K + k0 + 8 * g);
        }
        __syncthreads();
#pragma unroll
        for (int s = 0; s < 4; ++s) {
            bf16x8 av[2], bv[NWN];
#pragma unroll
            for (int mi = 0; mi < 2; ++mi) {
                int r = wr + mi * 32 + ln;
                av[mi] = *(const bf16x8*)((const char*)sA + r * 128 +
                                          ((((s << 1) | hi) ^ (r & 7)) << 4));
            }
#pragma unroll
            for (int ni = 0; ni < NWN; ++ni) {
                int r = wc + ni * 32 + ln;
                bv[ni] = *(const bf16x8*)((const char*)sB + r * 128 +
                                          ((((s << 1) | hi) ^ (r & 7)) << 4));
            }
#pragma unroll
            for (int mi = 0; mi < 2; ++mi)
#pragma unroll
                for (int ni = 0; ni < NWN; ++ni)
                    acc[mi][ni] = mfma32(av[mi], bv[ni], acc[mi][ni]);
        }
    }

    // epilogue: C/D layout col=lane&31, row=(r&3)+8*(r>>2)+4*hi (m74/m101)
#pragma unroll
    for (int mi = 0; mi < 2; ++mi)
#pragma unroll
        for (int ni = 0; ni < NWN; ++ni)
#pragma unroll
            for (int r = 0; r < 16; ++r) {
                int row = m0 + wr + mi * 32 + (r & 3) + 8 * (r >> 2) + 4 * hi;
                int col = n0 + wc + ni * 32 + ln;
                float v = acc[mi][ni][r];
                if (EPI == 0) {
                    int part = col >> 10, h = (col >> 6) & 15, d = col & 63;
                    int b = row >> 11, t = row & (T_ - 1);
                    size_t idx = ((size_t)(b * H_ + h) * T_ + t) * HD_ + d;
                    bf16* dst = (part == 0) ? qb : (part == 1) ? kb : vb;
                    dst[idx] = (bf16)v;
                } else {
                    outf[(size_t)row * N + col] = v + bias[col];
                }
            }
}

// ---------------- flash attention: swapped-operand 32x32 MFMA ----------------
__device__ __forceinline__ bf16x8 kread(const char* base, int row, int s, int hi) {
    int b = (row * 128 + s * 32 + hi * 16) ^ ((row & 7) << 4);
    return *(const bf16x8*)(base + b);
}
__device__ __forceinline__ bf16x8 vread(const char* base, int row, int s, int hi) {
    int sw = (row & 7) << 4;
    int b0 = (row * 128 + s * 32 + hi * 8) ^ sw;
    int b1 = (row * 128 + s * 32 + hi * 8 + 16) ^ sw;
    bf16x4 lo = *(const bf16x4*)(base + b0);
    bf16x4 hi4 = *(const bf16x4*)(base + b1);
    return __builtin_shufflevector(lo, hi4, 0, 1, 2, 3, 4, 5, 6, 7);
}

__global__ __launch_bounds__(256) void attn_kernel(
    const bf16* __restrict__ qb, const bf16* __restrict__ kb,
    const bf16* __restrict__ vtb, bf16* __restrict__ ob) {
    __shared__ bf16 sK2[2][4096];  // [64 kv][64 hd], 128B rows, XOR-swizzled
    __shared__ bf16 sV2[2][4096];  // [64 d][64 kv], 128B rows, XOR-swizzled

    const int bx = blockIdx.x;
    const int bh = bx & 31;
    const int qt = (bx < 256) ? ((bx >> 5) & 7) : (15 - ((bx >> 5) & 7));
    const int b = bh >> 4, h = bh & 15;
    const int tid = threadIdx.x, wave = tid >> 6, lane = tid & 63;
    const int ln = lane & 31, hi = lane >> 5;
    const int qs = qt * 128 + wave * 32;
    const int qrow = qs + ln;
    const int ntiles = 2 * qt + 2;

    const bf16* Qg = qb + (size_t)bh * (T_ * HD_);
    const bf16* Kg = kb + (size_t)bh * (T_ * HD_);
    const bf16* Vtg = vtb + (size_t)bh * (HD_ * T_);

    bf16x8 qf[4];
#pragma unroll
    for (int s = 0; s < 4; ++s) {
        bf16x8 v = *(const bf16x8*)&Qg[(size_t)qrow * HD_ + s * 16 + hi * 8];
#pragma unroll
        for (int e = 0; e < 8; ++e) v[e] = (bf16)((float)v[e] * 0.125f);
        qf[s] = v;
    }

    const int srow = tid >> 3;
    const int scol = (tid & 7) * 8;
    const int kw0 = (srow * 128 + (tid & 7) * 16) ^ ((srow & 7) << 4);
    const int kw1 = ((srow + 32) * 128 + (tid & 7) * 16) ^ ((srow & 7) << 4);

    {
        bf16x8 k0 = *(const bf16x8*)&Kg[(size_t)srow * HD_ + scol];
        bf16x8 k1 = *(const bf16x8*)&Kg[(size_t)(srow + 32) * HD_ + scol];
        bf16x8 v0 = *(const bf16x8*)&Vtg[(size_t)srow * T_ + scol];
        bf16x8 v1 = *(const bf16x8*)&Vtg[(size_t)(srow + 32) * T_ + scol];
        *(bf16x8*)((char*)sK2[0] + kw0) = k0;
        *(bf16x8*)((char*)sK2[0] + kw1) = k1;
        *(bf16x8*)((char*)sV2[0] + kw0) = v0;
        *(bf16x8*)((char*)sV2[0] + kw1) = v1;
    }
    __syncthreads();

    const float NINF = -__builtin_inff();
    f32x16 oA = z16(), oB = z16();
    float mR = NINF, lR = 0.f;
    int cur = 0;

    for (int t = 0; t < ntiles; ++t) {
        bf16x8 kr0, kr1, vr0, vr1;
        const bool pf = (t + 1) < ntiles;
        if (pf) {
            int kv0 = (t + 1) * 64;
            kr0 = *(const bf16x8*)&Kg[(size_t)(kv0 + srow) * HD_ + scol];
            kr1 = *(const bf16x8*)&Kg[(size_t)(kv0 + srow + 32) * HD_ + scol];
            vr0 = *(const bf16x8*)&Vtg[(size_t)srow * T_ + kv0 + scol];
            vr1 = *(const bf16x8*)&Vtg[(size_t)(srow + 32) * T_ + kv0 + scol];
        }

        if (64 * t <= qs + 31) {
            const char* kbase = (const char*)sK2[cur];
            const char* vbase = (const char*)sV2[cur];

            f32x16 p0 = z16(), p1 = z16();
#pragma unroll
            for (int s = 0; s < 4; ++s) {
                bf16x8 a0 = kread(kbase, ln, s, hi);
                bf16x8 a1 = kread(kbase, ln + 32, s, hi);
                p0 = mfma32(a0, qf[s], p0);
                p1 = mfma32(a1, qf[s], p1);
            }

            if (64 * t + 63 > qs) {
                int kvb = 64 * t + 4 * hi;
#pragma unroll
                for (int r = 0; r < 16; ++r) {
                    int kvr = kvb + (r & 3) + 8 * (r >> 2);
                    if (kvr > qrow) p0[r] = NINF;
                    if (kvr + 32 > qrow) p1[r] = NINF;
                }
            }

            float mx0 = NINF, mx1 = NINF, mx2 = NINF, mx3 = NINF;
#pragma unroll
            for (int r = 0; r < 16; r += 4) {
                mx0 = fmaxf(mx0, p0[r]);     mx1 = fmaxf(mx1, p0[r + 1]);
                mx2 = fmaxf(mx2, p0[r + 2]); mx3 = fmaxf(mx3, p0[r + 3]);
                mx0 = fmaxf(mx0, p1[r]);     mx1 = fmaxf(mx1, p1[r + 1]);
                mx2 = fmaxf(mx2, p1[r + 2]); mx3 = fmaxf(mx3, p1[r + 3]);
            }
            float pm = fmaxf(fmaxf(mx0, mx1), fmaxf(mx2, mx3));
            pm = fmaxf(pm, __shfl_xor(pm, 32));
            float mnew = fmaxf(mR, pm);
            float fac = __expf(mR - mnew);
            mR = mnew;
            float s0 = 0.f, s1 = 0.f, s2 = 0.f, s3 = 0.f;
#pragma unroll
            for (int r = 0; r < 16; r += 4) {
                p0[r] = __expf(p0[r] - mnew);         s0 += p0[r];
                p0[r + 1] = __expf(p0[r + 1] - mnew); s1 += p0[r + 1];
                p0[r + 2] = __expf(p0[r + 2] - mnew); s2 += p0[r + 2];
                p0[r + 3] = __expf(p0[r + 3] - mnew); s3 += p0[r + 3];
                p1[r] = __expf(p1[r] - mnew);         s0 += p1[r];
                p1[r + 1] = __expf(p1[r + 1] - mnew); s1 += p1[r + 1];
                p1[r + 2] = __expf(p1[r + 2] - mnew); s2 += p1[r + 2];
                p1[r + 3] = __expf(p1[r + 3] - mnew); s3 += p1[r + 3];
            }
            float rs = (s0 + s1) + (s2 + s3);
            rs += __shfl_xor(rs, 32);
            lR = lR * fac + rs;
#pragma unroll
            for (int r = 0; r < 16; ++r) { oA[r] *= fac; oB[r] *= fac; }

            bf16x8 pa0, pa1, pa2, pa3;
#pragma unroll
            for (int e = 0; e < 8; ++e) {
                pa0[e] = (bf16)p0[e];
                pa1[e] = (bf16)p0[8 + e];
                pa2[e] = (bf16)p1[e];
                pa3[e] = (bf16)p1[8 + e];
            }

#pragma unroll
            for (int s = 0; s < 4; ++s) {
                bf16x8 pas = (s == 0) ? pa0 : (s == 1) ? pa1 : (s == 2) ? pa2 : pa3;
                oA = mfma32(vread(vbase, ln, s, hi), pas, oA);
                oB = mfma32(vread(vbase, ln + 32, s, hi), pas, oB);
            }
        }

        if (pf) {
            int nb = cur ^ 1;
            *(bf16x8*)((char*)sK2[nb] + kw0) = kr0;
            *(bf16x8*)((char*)sK2[nb] + kw1) = kr1;
            *(bf16x8*)((char*)sV2[nb] + kw0) = vr0;
            *(bf16x8*)((char*)sV2[nb] + kw1) = vr1;
        }
        __syncthreads();
        cur ^= 1;
    }

    float inv = 1.f / lR;
    bf16* orow = ob + ((size_t)(b * T_ + qrow)) * D_ + h * HD_;
#pragma unroll
    for (int g = 0; g < 4; ++g) {
        bf16x4 w, w2;
#pragma unroll
        for (int j = 0; j < 4; ++j) {
            w[j] = (bf16)(oA[4 * g + j] * inv);
            w2[j] = (bf16)(oB[4 * g + j] * inv);
        }
        *(bf16x4*)&orow[4 * hi + 8 * g] = w;
        *(bf16x4*)&orow[32 + 4 * hi + 8 * g] = w2;
    }
}

// ---------------- launch ----------------
extern "C" void kernel_launch(void* const* d_in, const int* in_sizes, int n_in,
                              void* d_out, int out_size, void* d_ws, size_t ws_size,
                              hipStream_t stream) {
    const float* x = (const float*)d_in[0];
    const float* w_qkv = (const float*)d_in[1];
    const float* w_proj = (const float*)d_in[2];
    const float* b_proj = (const float*)d_in[3];
    float* out = (float*)d_out;
    char* ws = (char*)d_ws;

    // ws layout (40 MB total, aliased by liveness):
    bf16* xb = (bf16*)(ws);                 // [4096][1024]  8MB ; dead after GEMM1
    bf16* ob = (bf16*)(ws);                 // alias: attn out (written after xb dead)
    bf16* wqkvt = (bf16*)(ws + 8388608);    // [3072][1024]  6MB ; dead after GEMM1
    bf16* vtbuf = (bf16*)(ws + 8388608);    // alias: [bh][64][T] 8MB (written after GEMM1)
    bf16* qbuf = (bf16*)(ws + 16777216);    // [bh][T][64]   8MB ; dead after attn
    bf16* wprojt = (bf16*)(ws + 16777216);  // alias: [1024][1024] 2MB (written after attn)
    bf16* kbuf = (bf16*)(ws + 25165824);    // [bh][T][64]   8MB
    bf16* vbuf = (bf16*)(ws + 33554432);    // [bh][T][64]   8MB

    cast_f32_bf16<<<4096, 256, 0, stream>>>(x, xb, (B_ * T_ * D_) / 4);
    dim3 tb(32, 8);
    cast_transpose<<<dim3(3 * D_ / 32, D_ / 32), tb, 0, stream>>>(w_qkv, wqkvt, D_, 3 * D_);

    // GEMM1: 4096 x 3072 x 1024, block 128x256
    gemm_k<4, 0><<<dim3((B_ * T_) / 128, (3 * D_) / 256), 256, 0, stream>>>(
        xb, wqkvt, B_ * T_, 3 * D_, D_, qbuf, kbuf, vbuf, nullptr, nullptr);

    transpose_v<<<dim3(T_ / 64, B_ * H_), 256, 0, stream>>>(vbuf, vtbuf);

    attn_kernel<<<512, 256, 0, stream>>>(qbuf, kbuf, vtbuf, ob);

    cast_transpose<<<dim3(D_ / 32, D_ / 32), tb, 0, stream>>>(w_proj, wprojt, D_, D_);

    // GEMM2: 4096 x 1024 x 1024, block 128x128 (grid 256 = 1/CU)
    gemm_k<2, 1><<<dim3((B_ * T_) / 128, D_ / 128), 256, 0, stream>>>(
        ob, wprojt, B_ * T_, D_, D_, nullptr, nullptr, nullptr, b_proj, out);
}

// Round 5
// 129.911 us; speedup vs baseline: 2.3577x; 1.0865x over previous
//
#include <hip/hip_runtime.h>
#include <hip/hip_bf16.h>

// Fused causal MHA: qkv proj -> flash attention -> out proj, all bf16 MFMA.
// B=2 T=2048 D=1024 H=16 hd=64, scale=0.125 folded into Q (exact pow2).

typedef __bf16 bf16;
typedef float f32x4 __attribute__((ext_vector_type(4)));
typedef float f32x16 __attribute__((ext_vector_type(16)));
typedef bf16 bf16x4 __attribute__((ext_vector_type(4)));
typedef bf16 bf16x8 __attribute__((ext_vector_type(8)));

#define B_ 2
#define T_ 2048
#define D_ 1024
#define H_ 16
#define HD_ 64

__device__ __forceinline__ f32x16 mfma32(bf16x8 a, bf16x8 b, f32x16 c) {
    return __builtin_amdgcn_mfma_f32_32x32x16_bf16(a, b, c, 0, 0, 0);
}

// async global->LDS, 16B per lane (wave-uniform LDS base + lane*16)
__device__ __forceinline__ void gload16(void* l, const void* g) {
    __builtin_amdgcn_global_load_lds(
        (const __attribute__((address_space(1))) unsigned int*)g,
        (__attribute__((address_space(3))) unsigned int*)l, 16, 0, 0);
}

__device__ __forceinline__ f32x16 z16() {
    f32x16 v;
#pragma unroll
    for (int i = 0; i < 16; ++i) v[i] = 0.f;
    return v;
}

// ---------------- cast kernels ----------------
__global__ __launch_bounds__(256) void cast_f32_bf16(const float* __restrict__ in,
                                                     bf16* __restrict__ out, int n4) {
    int i = blockIdx.x * 256 + threadIdx.x;
    if (i < n4) {
        float4 v = ((const float4*)in)[i];
        bf16x4 o = { (bf16)v.x, (bf16)v.y, (bf16)v.z, (bf16)v.w };
        ((bf16x4*)out)[i] = o;
    }
}

// in [R][C] f32 -> out [C][R] bf16
__global__ __launch_bounds__(256) void cast_transpose(const float* __restrict__ in,
                                                      bf16* __restrict__ out, int R, int C) {
    __shared__ float tile[32][33];
    int cx = blockIdx.x * 32 + threadIdx.x;
    int r0 = blockIdx.y * 32;
#pragma unroll
    for (int j = 0; j < 32; j += 8)
        tile[threadIdx.y + j][threadIdx.x] = in[(size_t)(r0 + threadIdx.y + j) * C + cx];
    __syncthreads();
    int rx = r0 + threadIdx.x;
    int c0 = blockIdx.x * 32;
#pragma unroll
    for (int j = 0; j < 32; j += 8)
        out[(size_t)(c0 + threadIdx.y + j) * R + rx] = (bf16)tile[threadIdx.x][threadIdx.y + j];
}

// V [bh][T][64] bf16 -> Vt [bh][64][T] bf16 (64x64 tiles, conflict-free LDS)
__global__ __launch_bounds__(256) void transpose_v(const bf16* __restrict__ vb,
                                                   bf16* __restrict__ vt) {
    __shared__ bf16 st[64 * 65];
    const int bh = blockIdx.y;
    const int t0 = blockIdx.x * 64;
    const int tid = threadIdx.x;
#pragma unroll
    for (int c = 0; c < 2; ++c) {
        int cid = tid + c * 256;
        int r = cid >> 3, col = (cid & 7) * 8;
        bf16x8 v = *(const bf16x8*)&vb[((size_t)bh * T_ + t0 + r) * HD_ + col];
#pragma unroll
        for (int j = 0; j < 8; ++j) st[r * 65 + col + j] = v[j];
    }
    __syncthreads();
#pragma unroll
    for (int c = 0; c < 2; ++c) {
        int cid = tid + c * 256;
        int tg = cid & 7, d = cid >> 3;
        bf16x8 o;
#pragma unroll
        for (int j = 0; j < 8; ++j) o[j] = st[(tg * 8 + j) * 65 + d];
        *(bf16x8*)&vt[((size_t)bh * HD_ + d) * T_ + t0 + tg * 8] = o;
    }
}

// ---------------- GEMM: C[M,N] = A[M,K] * Bt[N,K]^T, 32x32x16 MFMA ----------------
// Block tile (64*MW) x (64*NWN); 4 waves (2M x 2N), per-wave (32*MW) x (32*NWN).
// BK=64. LDS layout: [row][64] with chunk swizzle p = g ^ (row&7) (16B chunks);
// staged via global_load_lds with inverse-permuted SOURCE (linear dest, rule #21).
// Fragments: 16B-contiguous k-packing (hi,e)->k=16s+8hi+e, identical for A and B
// (self-consistent => correct; hardware-validated across rounds 2-4).
// EPI 0: scatter qkv into per-head Q/K/V [B][H][T][64] bf16 ; EPI 1: +bias, f32 out.
template <int MW, int NWN, int EPI>
__global__ __launch_bounds__(256) void gemm_k(
    const bf16* __restrict__ A, const bf16* __restrict__ Bt,
    int M, int N, int K,
    bf16* __restrict__ qb, bf16* __restrict__ kb, bf16* __restrict__ vb,
    const float* __restrict__ bias, float* __restrict__ outf) {
    constexpr int BM = 64 * MW;
    constexpr int BN = 64 * NWN;
    __shared__ bf16 sA[BM * 64];
    __shared__ bf16 sB[BN * 64];
    const int tid = threadIdx.x;
    const int wave = tid >> 6, lane = tid & 63;
    const int ln = lane & 31, hi = lane >> 5;
    const int wr = (wave >> 1) * (32 * MW);
    const int wc = (wave & 1) * (32 * NWN);
    const int m0 = blockIdx.x * BM, n0 = blockIdx.y * BN;

    f32x16 acc[MW][NWN];
#pragma unroll
    for (int mi = 0; mi < MW; ++mi)
#pragma unroll
        for (int ni = 0; ni < NWN; ++ni) acc[mi][ni] = z16();

    for (int k0 = 0; k0 < K; k0 += 64) {
        __syncthreads();
#pragma unroll
        for (int j = 0; j < 2 * MW; ++j) {
            int c = tid + 256 * j;
            int r = c >> 3, g = (c & 7) ^ (r & 7);
            gload16(&sA[c * 8], A + (size_t)(m0 + r) * K + k0 + 8 * g);
        }
#pragma unroll
        for (int j = 0; j < 2 * NWN; ++j) {
            int c = tid + 256 * j;
            int r = c >> 3, g = (c & 7) ^ (r & 7);
            gload16(&sB[c * 8], Bt + (size_t)(n0 + r) * K + k0 + 8 * g);
        }
        __syncthreads();
#pragma unroll
        for (int s = 0; s < 4; ++s) {
            bf16x8 av[MW], bv[NWN];
#pragma unroll
            for (int mi = 0; mi < MW; ++mi) {
                int r = wr + mi * 32 + ln;
                av[mi] = *(const bf16x8*)((const char*)sA + r * 128 +
                                          ((((s << 1) | hi) ^ (r & 7)) << 4));
            }
#pragma unroll
            for (int ni = 0; ni < NWN; ++ni) {
                int r = wc + ni * 32 + ln;
                bv[ni] = *(const bf16x8*)((const char*)sB + r * 128 +
                                          ((((s << 1) | hi) ^ (r & 7)) << 4));
            }
#pragma unroll
            for (int mi = 0; mi < MW; ++mi)
#pragma unroll
                for (int ni = 0; ni < NWN; ++ni)
                    acc[mi][ni] = mfma32(av[mi], bv[ni], acc[mi][ni]);
        }
    }

    // epilogue: C/D layout col=lane&31, row=(r&3)+8*(r>>2)+4*hi (m74/m101)
#pragma unroll
    for (int mi = 0; mi < MW; ++mi)
#pragma unroll
        for (int ni = 0; ni < NWN; ++ni)
#pragma unroll
            for (int r = 0; r < 16; ++r) {
                int row = m0 + wr + mi * 32 + (r & 3) + 8 * (r >> 2) + 4 * hi;
                int col = n0 + wc + ni * 32 + ln;
                float v = acc[mi][ni][r];
                if (EPI == 0) {
                    int part = col >> 10, h = (col >> 6) & 15, d = col & 63;
                    int b = row >> 11, t = row & (T_ - 1);
                    size_t idx = ((size_t)(b * H_ + h) * T_ + t) * HD_ + d;
                    bf16* dst = (part == 0) ? qb : (part == 1) ? kb : vb;
                    dst[idx] = (bf16)v;
                } else {
                    outf[(size_t)row * N + col] = v + bias[col];
                }
            }
}

// ---------------- flash attention: swapped-operand 32x32 MFMA ----------------
// Softmax runs in log2 domain: Q pre-scaled by 0.125*log2(e); exp2f -> native
// v_exp_f32 with no per-element pre-multiply.
__device__ __forceinline__ bf16x8 kread(const char* base, int row, int s, int hi) {
    int b = (row * 128 + s * 32 + hi * 16) ^ ((row & 7) << 4);
    return *(const bf16x8*)(base + b);
}
__device__ __forceinline__ bf16x8 vread(const char* base, int row, int s, int hi) {
    int sw = (row & 7) << 4;
    int b0 = (row * 128 + s * 32 + hi * 8) ^ sw;
    int b1 = (row * 128 + s * 32 + hi * 8 + 16) ^ sw;
    bf16x4 lo = *(const bf16x4*)(base + b0);
    bf16x4 hi4 = *(const bf16x4*)(base + b1);
    return __builtin_shufflevector(lo, hi4, 0, 1, 2, 3, 4, 5, 6, 7);
}

__global__ __launch_bounds__(256) void attn_kernel(
    const bf16* __restrict__ qb, const bf16* __restrict__ kb,
    const bf16* __restrict__ vtb, bf16* __restrict__ ob) {
    __shared__ bf16 sK2[2][4096];  // [64 kv][64 hd], 128B rows, XOR-swizzled
    __shared__ bf16 sV2[2][4096];  // [64 d][64 kv], 128B rows, XOR-swizzled

    const int bx = blockIdx.x;
    const int bh = bx & 31;
    const int qt = (bx < 256) ? ((bx >> 5) & 7) : (15 - ((bx >> 5) & 7));
    const int b = bh >> 4, h = bh & 15;
    const int tid = threadIdx.x, wave = tid >> 6, lane = tid & 63;
    const int ln = lane & 31, hi = lane >> 5;
    const int qs = qt * 128 + wave * 32;
    const int qrow = qs + ln;
    const int ntiles = 2 * qt + 2;

    const bf16* Qg = qb + (size_t)bh * (T_ * HD_);
    const bf16* Kg = kb + (size_t)bh * (T_ * HD_);
    const bf16* Vtg = vtb + (size_t)bh * (HD_ * T_);

    // Q fragments, scale 0.125*log2(e) folded in (softmax in log2 domain)
    bf16x8 qf[4];
#pragma unroll
    for (int s = 0; s < 4; ++s) {
        bf16x8 v = *(const bf16x8*)&Qg[(size_t)qrow * HD_ + s * 16 + hi * 8];
#pragma unroll
        for (int e = 0; e < 8; ++e) v[e] = (bf16)((float)v[e] * 0.1803368801f);
        qf[s] = v;
    }

    const int srow = tid >> 3;
    const int scol = (tid & 7) * 8;
    const int kw0 = (srow * 128 + (tid & 7) * 16) ^ ((srow & 7) << 4);
    const int kw1 = ((srow + 32) * 128 + (tid & 7) * 16) ^ ((srow & 7) << 4);

    {
        bf16x8 k0 = *(const bf16x8*)&Kg[(size_t)srow * HD_ + scol];
        bf16x8 k1 = *(const bf16x8*)&Kg[(size_t)(srow + 32) * HD_ + scol];
        bf16x8 v0 = *(const bf16x8*)&Vtg[(size_t)srow * T_ + scol];
        bf16x8 v1 = *(const bf16x8*)&Vtg[(size_t)(srow + 32) * T_ + scol];
        *(bf16x8*)((char*)sK2[0] + kw0) = k0;
        *(bf16x8*)((char*)sK2[0] + kw1) = k1;
        *(bf16x8*)((char*)sV2[0] + kw0) = v0;
        *(bf16x8*)((char*)sV2[0] + kw1) = v1;
    }
    __syncthreads();

    const float NINF = -__builtin_inff();
    f32x16 oA = z16(), oB = z16();
    float mR = NINF, lR = 0.f;
    int cur = 0;

    for (int t = 0; t < ntiles; ++t) {
        bf16x8 kr0, kr1, vr0, vr1;
        const bool pf = (t + 1) < ntiles;
        if (pf) {
            int kv0 = (t + 1) * 64;
            kr0 = *(const bf16x8*)&Kg[(size_t)(kv0 + srow) * HD_ + scol];
            kr1 = *(const bf16x8*)&Kg[(size_t)(kv0 + srow + 32) * HD_ + scol];
            vr0 = *(const bf16x8*)&Vtg[(size_t)srow * T_ + kv0 + scol];
            vr1 = *(const bf16x8*)&Vtg[(size_t)(srow + 32) * T_ + kv0 + scol];
        }

        if (64 * t <= qs + 31) {
            const char* kbase = (const char*)sK2[cur];
            const char* vbase = (const char*)sV2[cur];

            f32x16 p0 = z16(), p1 = z16();
#pragma unroll
            for (int s = 0; s < 4; ++s) {
                bf16x8 a0 = kread(kbase, ln, s, hi);
                bf16x8 a1 = kread(kbase, ln + 32, s, hi);
                p0 = mfma32(a0, qf[s], p0);
                p1 = mfma32(a1, qf[s], p1);
            }

            if (64 * t + 63 > qs) {
                int kvb = 64 * t + 4 * hi;
#pragma unroll
                for (int r = 0; r < 16; ++r) {
                    int kvr = kvb + (r & 3) + 8 * (r >> 2);
                    if (kvr > qrow) p0[r] = NINF;
                    if (kvr + 32 > qrow) p1[r] = NINF;
                }
            }

            float mx0 = NINF, mx1 = NINF, mx2 = NINF, mx3 = NINF;
#pragma unroll
            for (int r = 0; r < 16; r += 4) {
                mx0 = fmaxf(mx0, p0[r]);     mx1 = fmaxf(mx1, p0[r + 1]);
                mx2 = fmaxf(mx2, p0[r + 2]); mx3 = fmaxf(mx3, p0[r + 3]);
                mx0 = fmaxf(mx0, p1[r]);     mx1 = fmaxf(mx1, p1[r + 1]);
                mx2 = fmaxf(mx2, p1[r + 2]); mx3 = fmaxf(mx3, p1[r + 3]);
            }
            float pm = fmaxf(fmaxf(mx0, mx1), fmaxf(mx2, mx3));
            pm = fmaxf(pm, __shfl_xor(pm, 32));
            float mnew = fmaxf(mR, pm);
            float fac = exp2f(mR - mnew);
            mR = mnew;
            float s0 = 0.f, s1 = 0.f, s2 = 0.f, s3 = 0.f;
#pragma unroll
            for (int r = 0; r < 16; r += 4) {
                p0[r] = exp2f(p0[r] - mnew);         s0 += p0[r];
                p0[r + 1] = exp2f(p0[r + 1] - mnew); s1 += p0[r + 1];
                p0[r + 2] = exp2f(p0[r + 2] - mnew); s2 += p0[r + 2];
                p0[r + 3] = exp2f(p0[r + 3] - mnew); s3 += p0[r + 3];
                p1[r] = exp2f(p1[r] - mnew);         s0 += p1[r];
                p1[r + 1] = exp2f(p1[r + 1] - mnew); s1 += p1[r + 1];
                p1[r + 2] = exp2f(p1[r + 2] - mnew); s2 += p1[r + 2];
                p1[r + 3] = exp2f(p1[r + 3] - mnew); s3 += p1[r + 3];
            }
            float rs = (s0 + s1) + (s2 + s3);
            rs += __shfl_xor(rs, 32);
            lR = lR * fac + rs;
#pragma unroll
            for (int r = 0; r < 16; ++r) { oA[r] *= fac; oB[r] *= fac; }

            bf16x8 pa0, pa1, pa2, pa3;
#pragma unroll
            for (int e = 0; e < 8; ++e) {
                pa0[e] = (bf16)p0[e];
                pa1[e] = (bf16)p0[8 + e];
                pa2[e] = (bf16)p1[e];
                pa3[e] = (bf16)p1[8 + e];
            }

#pragma unroll
            for (int s = 0; s < 4; ++s) {
                bf16x8 pas = (s == 0) ? pa0 : (s == 1) ? pa1 : (s == 2) ? pa2 : pa3;
                oA = mfma32(vread(vbase, ln, s, hi), pas, oA);
                oB = mfma32(vread(vbase, ln + 32, s, hi), pas, oB);
            }
        }

        if (pf) {
            int nb = cur ^ 1;
            *(bf16x8*)((char*)sK2[nb] + kw0) = kr0;
            *(bf16x8*)((char*)sK2[nb] + kw1) = kr1;
            *(bf16x8*)((char*)sV2[nb] + kw0) = vr0;
            *(bf16x8*)((char*)sV2[nb] + kw1) = vr1;
        }
        __syncthreads();
        cur ^= 1;
    }

    float inv = 1.f / lR;
    bf16* orow = ob + ((size_t)(b * T_ + qrow)) * D_ + h * HD_;
#pragma unroll
    for (int g = 0; g < 4; ++g) {
        bf16x4 w, w2;
#pragma unroll
        for (int j = 0; j < 4; ++j) {
            w[j] = (bf16)(oA[4 * g + j] * inv);
            w2[j] = (bf16)(oB[4 * g + j] * inv);
        }
        *(bf16x4*)&orow[4 * hi + 8 * g] = w;
        *(bf16x4*)&orow[32 + 4 * hi + 8 * g] = w2;
    }
}

// ---------------- launch ----------------
extern "C" void kernel_launch(void* const* d_in, const int* in_sizes, int n_in,
                              void* d_out, int out_size, void* d_ws, size_t ws_size,
                              hipStream_t stream) {
    const float* x = (const float*)d_in[0];
    const float* w_qkv = (const float*)d_in[1];
    const float* w_proj = (const float*)d_in[2];
    const float* b_proj = (const float*)d_in[3];
    float* out = (float*)d_out;
    char* ws = (char*)d_ws;

    // ws layout (40 MB total, aliased by liveness):
    bf16* xb = (bf16*)(ws);                 // [4096][1024]  8MB ; dead after GEMM1
    bf16* ob = (bf16*)(ws);                 // alias: attn out (written after xb dead)
    bf16* wqkvt = (bf16*)(ws + 8388608);    // [3072][1024]  6MB ; dead after GEMM1
    bf16* vtbuf = (bf16*)(ws + 8388608);    // alias: [bh][64][T] 8MB (written after GEMM1)
    bf16* qbuf = (bf16*)(ws + 16777216);    // [bh][T][64]   8MB ; dead after attn
    bf16* wprojt = (bf16*)(ws + 16777216);  // alias: [1024][1024] 2MB (written after attn)
    bf16* kbuf = (bf16*)(ws + 25165824);    // [bh][T][64]   8MB
    bf16* vbuf = (bf16*)(ws + 33554432);    // [bh][T][64]   8MB

    cast_f32_bf16<<<4096, 256, 0, stream>>>(x, xb, (B_ * T_ * D_) / 4);
    dim3 tb(32, 8);
    cast_transpose<<<dim3(3 * D_ / 32, D_ / 32), tb, 0, stream>>>(w_qkv, wqkvt, D_, 3 * D_);

    // GEMM1: 4096 x 3072 x 1024, block 128x128 -> grid 768 = 3 blocks/CU
    gemm_k<2, 2, 0><<<dim3((B_ * T_) / 128, (3 * D_) / 128), 256, 0, stream>>>(
        xb, wqkvt, B_ * T_, 3 * D_, D_, qbuf, kbuf, vbuf, nullptr, nullptr);

    transpose_v<<<dim3(T_ / 64, B_ * H_), 256, 0, stream>>>(vbuf, vtbuf);

    attn_kernel<<<512, 256, 0, stream>>>(qbuf, kbuf, vtbuf, ob);

    cast_transpose<<<dim3(D_ / 32, D_ / 32), tb, 0, stream>>>(w_proj, wprojt, D_, D_);

    // GEMM2: 4096 x 1024 x 1024, block 64x128 -> grid 512 = 2 blocks/CU
    gemm_k<1, 2, 1><<<dim3((B_ * T_) / 64, D_ / 128), 256, 0, stream>>>(
        ob, wprojt, B_ * T_, D_, D_, nullptr, nullptr, nullptr, b_proj, out);
}